// Round 7
// baseline (188.698 us; speedup 1.0000x reference)
//
#include <hip/hip_runtime.h>

#define LOG2PI 1.83787706640934548356f

typedef __attribute__((ext_vector_type(4))) float f32x4;
typedef __attribute__((ext_vector_type(2))) float f32x2;
typedef __attribute__((ext_vector_type(8))) short bf16x8;

__device__ __forceinline__ unsigned short f2bf(float f) {
    union { float f; unsigned u; } v; v.f = f;
    unsigned r = v.u + 0x7fffu + ((v.u >> 16) & 1u);   // RNE
    return (unsigned short)(r >> 16);
}
__device__ __forceinline__ float bf2f(unsigned short h) {
    union { unsigned u; float f; } v; v.u = ((unsigned)h) << 16; return v.f;
}
__device__ __forceinline__ bf16x8 pack8(f32x4 a, f32x4 b) {
    bf16x8 h;
    h[0]=(short)f2bf(a[0]); h[1]=(short)f2bf(a[1]); h[2]=(short)f2bf(a[2]); h[3]=(short)f2bf(a[3]);
    h[4]=(short)f2bf(b[0]); h[5]=(short)f2bf(b[1]); h[6]=(short)f2bf(b[2]); h[7]=(short)f2bf(b[3]);
    return h;
}
// sum within each 16-lane DPP row; valid in lane 15 of each row (VALU pipe, no LDS)
__device__ __forceinline__ float rowsum16(float v) {
    v += __int_as_float(__builtin_amdgcn_update_dpp(0, __float_as_int(v), 0x111, 0xf, 0xf, true));
    v += __int_as_float(__builtin_amdgcn_update_dpp(0, __float_as_int(v), 0x112, 0xf, 0xf, true));
    v += __int_as_float(__builtin_amdgcn_update_dpp(0, __float_as_int(v), 0x114, 0xf, 0xf, true));
    v += __int_as_float(__builtin_amdgcn_update_dpp(0, __float_as_int(v), 0x118, 0xf, 0xf, true));
    return v;
}

// bias[c] = lp[c] - 0.5*(sum(clv[c,:]) + 256*log(2pi))
__global__ __launch_bounds__(256)
void k_prep(const float* __restrict__ clv, const float* __restrict__ lp,
            float* __restrict__ bias)
{
    const int w = threadIdx.x >> 6, lane = threadIdx.x & 63;
    const int c = blockIdx.x * 4 + w;
    if (c >= 1000) return;
    f32x4 v = *reinterpret_cast<const f32x4*>(clv + c * 256 + lane * 4);
    float s = v[0] + v[1] + v[2] + v[3];
    #pragma unroll
    for (int m = 1; m < 64; m <<= 1) s += __shfl_xor(s, m);
    if (lane == 0) bias[c] = lp[c] - 0.5f * (s + 256.0f * LOG2PI);
}

// Two blocks per batch (q = bid&1 owns d in [128q, 128q+128)). 8 waves:
// wm = wave>>2 (16-class row half of 32-class chunk), wn = wave&3 (32-col group).
// G half held in registers as MFMA B-fragments (greg[2][8] = 64 VGPR -> 4 waves/SIMD).
// LDS: double-buffered 32-class diff chunk, SoA-slice [slice][row][16B] (conflict-free
// b128 r/w) + per-block maha partials. Cross-block reduce via global atomicAdd to ws.
__global__ __launch_bounds__(512, 4)
void k_main(const float* __restrict__ x, const float* __restrict__ G,
            const float* __restrict__ means, float* __restrict__ maha_ws)
{
    __shared__ char dbuf[2][16384];
    __shared__ float maha[1024];

    const int b    = blockIdx.x >> 1;
    const int q    = blockIdx.x & 1;     // d-half
    const int tid  = threadIdx.x;
    const int lane = tid & 63;
    const int wave = tid >> 6;
    const int wm   = wave >> 2;
    const int wn   = wave & 3;
    const int lrow = lane & 15;
    const int g    = lane >> 4;
    const int d0   = q * 128;

    const float* Gb = G + (size_t)b * 65536;
    const float* xb = x + b * 256;

    maha[tid] = 0.f; maha[tid + 512] = 0.f;

    // ---- G -> register B-fragments: greg[n][ks], lane holds
    //      G[d = d0 + 32wn + 16n + lrow][e = 32ks + 8g .. +8)
    bf16x8 greg[2][8];
    #pragma unroll
    for (int n = 0; n < 2; ++n) {
        const float* rowp = Gb + (size_t)(d0 + wn * 32 + n * 16 + lrow) * 256 + g * 8;
        #pragma unroll
        for (int ks = 0; ks < 8; ++ks) {
            f32x4 v0 = *reinterpret_cast<const f32x4*>(rowp + ks * 32);
            f32x4 v1 = *reinterpret_cast<const f32x4*>(rowp + ks * 32 + 4);
            greg[n][ks] = pack8(v0, v1);
        }
    }

    // staging map: row sr = tid&31, slices ss and ss+16 (ss = tid>>5 in 0..15)
    const int sr = tid & 31;
    const int ss = tid >> 5;
    const f32x4 x0a = *reinterpret_cast<const f32x4*>(xb + ss * 8);
    const f32x4 x0b = *reinterpret_cast<const f32x4*>(xb + ss * 8 + 4);
    const f32x4 x1a = *reinterpret_cast<const f32x4*>(xb + (ss + 16) * 8);
    const f32x4 x1b = *reinterpret_cast<const f32x4*>(xb + (ss + 16) * 8 + 4);

    f32x4 r0a, r0b, r1a, r1b;
    auto load_chunk = [&](int c0) {
        int cc = c0 + sr; if (cc > 999) cc = 999;
        const float* mp = means + (size_t)cc * 256;
        r0a = *reinterpret_cast<const f32x4*>(mp + ss * 8);
        r0b = *reinterpret_cast<const f32x4*>(mp + ss * 8 + 4);
        r1a = *reinterpret_cast<const f32x4*>(mp + (ss + 16) * 8);
        r1b = *reinterpret_cast<const f32x4*>(mp + (ss + 16) * 8 + 4);
    };
    auto write_chunk = [&](int bufi) {
        *reinterpret_cast<bf16x8*>(dbuf[bufi] + (ss * 32 + sr) * 16)        = pack8(x0a - r0a, x0b - r0b);
        *reinterpret_cast<bf16x8*>(dbuf[bufi] + ((ss + 16) * 32 + sr) * 16) = pack8(x1a - r1a, x1b - r1b);
    };

    load_chunk(0);

    for (int t = 0; t < 32; ++t) {
        write_chunk(t & 1);
        __syncthreads();                        // readers of both buffers are past
        if (t < 31) load_chunk((t + 1) * 32);   // T14: issue early, consume next top

        const char* buf = dbuf[t & 1];
        f32x4 acc[2];
        acc[0] = f32x4{0.f, 0.f, 0.f, 0.f};
        acc[1] = f32x4{0.f, 0.f, 0.f, 0.f};

        #pragma unroll
        for (int ks = 0; ks < 8; ++ks) {
            // A-frag: diff[row = 16wm + lrow][e = 32ks + 8g ..) — 16-lane contiguous
            bf16x8 afr = *reinterpret_cast<const bf16x8*>(
                buf + ((ks * 4 + g) * 32 + wm * 16 + lrow) * 16);
            acc[0] = __builtin_amdgcn_mfma_f32_16x16x32_bf16(afr, greg[0][ks], acc[0], 0, 0, 0);
            acc[1] = __builtin_amdgcn_mfma_f32_16x16x32_bf16(afr, greg[1][ks], acc[1], 0, 0, 0);
        }

        // epilogue: p_i = sum over this wave's 32 cols of T[c,d]*diff[c,d]
        float p[4] = {0.f, 0.f, 0.f, 0.f};
        #pragma unroll
        for (int n = 0; n < 2; ++n) {
            const int col = d0 + wn * 32 + n * 16 + lrow;   // global d in [0,256)
            const char* dp = buf + ((col >> 3) * 32) * 16 + (col & 7) * 2;
            #pragma unroll
            for (int i = 0; i < 4; ++i) {
                const int row = wm * 16 + g * 4 + i;
                p[i] += acc[n][i] * bf2f(*reinterpret_cast<const unsigned short*>(dp + row * 16));
            }
        }
        #pragma unroll
        for (int i = 0; i < 4; ++i) p[i] = rowsum16(p[i]);
        if (lrow == 15) {
            const int c = t * 32 + wm * 16 + g * 4;
            #pragma unroll
            for (int i = 0; i < 4; ++i)
                if (c + i < 1000) atomicAdd(&maha[c + i], p[i]);
        }
    }

    __syncthreads();
    // flush this block's partial maha to global (cross d-half reduction)
    for (int i = tid; i < 1000; i += 512)
        atomicAdd(&maha_ws[(size_t)b * 1000 + i], maha[i]);
}

__global__ __launch_bounds__(256)
void k_soft(const float* __restrict__ maha_ws, const float* __restrict__ bias,
            float* __restrict__ out)
{
    __shared__ float red[4];
    const int b = blockIdx.x, tid = threadIdx.x;
    const int lane = tid & 63, w = tid >> 6;
    float s[4];
    float mx = -3.4e38f;
    #pragma unroll
    for (int i = 0; i < 4; ++i) {
        const int c = tid + i * 256;
        if (c < 1000) {
            float v = -0.5f * maha_ws[(size_t)b * 1000 + c] + bias[c];
            s[i] = v; mx = fmaxf(mx, v);
        } else s[i] = -3.4e38f;
    }
    #pragma unroll
    for (int m = 1; m < 64; m <<= 1) mx = fmaxf(mx, __shfl_xor(mx, m));
    if (lane == 0) red[w] = mx;
    __syncthreads();
    const float bm = fmaxf(fmaxf(red[0], red[1]), fmaxf(red[2], red[3]));
    __syncthreads();
    float se = 0.f;
    #pragma unroll
    for (int i = 0; i < 4; ++i) {
        const int c = tid + i * 256;
        if (c < 1000) se += expf(s[i] - bm);
    }
    #pragma unroll
    for (int m = 1; m < 64; m <<= 1) se += __shfl_xor(se, m);
    if (lane == 0) red[w] = se;
    __syncthreads();
    const float lse = bm + logf(red[0] + red[1] + red[2] + red[3]);
    #pragma unroll
    for (int i = 0; i < 4; ++i) {
        const int c = tid + i * 256;
        if (c < 1000) out[(size_t)b * 1000 + c] = s[i] - lse;
    }
}

extern "C" void kernel_launch(void* const* d_in, const int* in_sizes, int n_in,
                              void* d_out, int out_size, void* d_ws, size_t ws_size,
                              hipStream_t stream)
{
    const float* x     = (const float*)d_in[0];
    const float* G     = (const float*)d_in[1];
    const float* lp    = (const float*)d_in[2];
    const float* means = (const float*)d_in[3];
    const float* clv   = (const float*)d_in[4];
    float* out     = (float*)d_out;
    float* maha_ws = (float*)d_ws;                 // 256*1000 f32 partial sums
    float* bias    = (float*)d_ws + 256 * 1000;    // 1000 f32

    hipMemsetAsync(maha_ws, 0, (size_t)256 * 1000 * sizeof(float), stream);
    k_prep<<<250, 256, 0, stream>>>(clv, lp, bias);
    k_main<<<512, 512, 0, stream>>>(x, G, means, maha_ws);
    k_soft<<<256, 256, 0, stream>>>(maha_ws, bias, out);
}

// Round 8
// 182.711 us; speedup vs baseline: 1.0328x; 1.0328x over previous
//
#include <hip/hip_runtime.h>

#define LOG2PI 1.83787706640934548356f

typedef __attribute__((ext_vector_type(4))) float f32x4;
typedef __attribute__((ext_vector_type(8))) short bf16x8;
typedef __attribute__((ext_vector_type(2))) unsigned int u32x2;

__device__ __forceinline__ unsigned short f2bf(float f) {
    union { float f; unsigned u; } v; v.f = f;
    unsigned r = v.u + 0x7fffu + ((v.u >> 16) & 1u);   // RNE
    return (unsigned short)(r >> 16);
}
__device__ __forceinline__ bf16x8 pack8(f32x4 a, f32x4 b) {
    bf16x8 h;
    h[0]=(short)f2bf(a[0]); h[1]=(short)f2bf(a[1]); h[2]=(short)f2bf(a[2]); h[3]=(short)f2bf(a[3]);
    h[4]=(short)f2bf(b[0]); h[5]=(short)f2bf(b[1]); h[6]=(short)f2bf(b[2]); h[7]=(short)f2bf(b[3]);
    return h;
}

// bias[c] = lp[c] - 0.5*(sum(clv[c,:]) + 256*log(2pi))
__global__ __launch_bounds__(256)
void k_prep(const float* __restrict__ clv, const float* __restrict__ lp,
            float* __restrict__ bias)
{
    const int w = threadIdx.x >> 6, lane = threadIdx.x & 63;
    const int c = blockIdx.x * 4 + w;
    if (c >= 1000) return;
    f32x4 v = *reinterpret_cast<const f32x4*>(clv + c * 256 + lane * 4);
    float s = v[0] + v[1] + v[2] + v[3];
    #pragma unroll
    for (int m = 1; m < 64; m <<= 1) s += __shfl_xor(s, m);
    if (lane == 0) bias[c] = lp[c] - 0.5f * (s + 256.0f * LOG2PI);
}

// grid = 256 batches x 4 class-groups (256 classes each). Block = 256 thr = 4 waves.
// Wave wn owns d in [64wn, 64wn+64): greg[4][8] = 128 VGPR (full K in regs).
// LDS: double-buffered 16-class diff chunk, [slice s 0..31][row r 0..15][16B] with
// r ^= (s&3)<<1 swizzle (conflict-free b128 reads across g-groups) + maha[256].
// MFMA swapped: acc = mfma(A=greg, B=diff) -> C[row=d-local, col=class]; lane owns
// ONE class (lrow) -> epilogue = 4x ds_read_b64 + in-lane fma + 2 shfl + 1 LDS atomic.
// Class-split => no cross-block reduction: maha flushed straight to out.
__global__ __launch_bounds__(256, 2)
void k_main(const float* __restrict__ x, const float* __restrict__ G,
            const float* __restrict__ means, float* __restrict__ out)
{
    __shared__ char dbuf[2][8192];
    __shared__ float maha[256];

    const int b     = blockIdx.x >> 2;
    const int cg    = blockIdx.x & 3;
    const int cbase = cg * 256;
    const int tid   = threadIdx.x;
    const int lane  = tid & 63;
    const int wn    = tid >> 6;          // wave = d-group
    const int lrow  = lane & 15;
    const int g     = lane >> 4;

    const float* Gb = G + (size_t)b * 65536;
    const float* xb = x + b * 256;

    maha[tid] = 0.f;

    // ---- G -> register A-fragments: greg[n][ks], lane holds
    //      G[d = 64wn + 16n + lrow][e = 32ks + 8g .. +8)
    bf16x8 greg[4][8];
    #pragma unroll
    for (int n = 0; n < 4; ++n) {
        const float* rowp = Gb + (size_t)(wn * 64 + n * 16 + lrow) * 256 + g * 8;
        #pragma unroll
        for (int ks = 0; ks < 8; ++ks) {
            f32x4 v0 = *reinterpret_cast<const f32x4*>(rowp + ks * 32);
            f32x4 v1 = *reinterpret_cast<const f32x4*>(rowp + ks * 32 + 4);
            greg[n][ks] = pack8(v0, v1);
        }
    }

    // staging map: thread owns cells (s0, sr) and (s0+16, sr); cell = 8 e-values of one class
    const int sr = tid & 15;             // class row within 16-class chunk
    const int s0 = tid >> 4;             // slice 0..15
    const int e0 = s0 * 8, e1 = e0 + 128;
    const f32x4 xa0 = *reinterpret_cast<const f32x4*>(xb + e0);
    const f32x4 xa1 = *reinterpret_cast<const f32x4*>(xb + e0 + 4);
    const f32x4 xb0 = *reinterpret_cast<const f32x4*>(xb + e1);
    const f32x4 xb1 = *reinterpret_cast<const f32x4*>(xb + e1 + 4);
    const int wbyte0 = (s0 * 16 + (sr ^ ((s0 & 3) << 1))) * 16;   // (s0+16)&3 == s0&3
    const int wbyte1 = wbyte0 + 4096;

    f32x4 r0a, r0b, r1a, r1b;
    auto load_chunk = [&](int c0) {
        int cc = cbase + c0 + sr; if (cc > 999) cc = 999;
        const float* mp = means + (size_t)cc * 256;
        r0a = *reinterpret_cast<const f32x4*>(mp + e0);
        r0b = *reinterpret_cast<const f32x4*>(mp + e0 + 4);
        r1a = *reinterpret_cast<const f32x4*>(mp + e1);
        r1b = *reinterpret_cast<const f32x4*>(mp + e1 + 4);
    };
    auto write_chunk = [&](int bufi) {
        *reinterpret_cast<bf16x8*>(dbuf[bufi] + wbyte0) = pack8(xa0 - r0a, xa1 - r0b);
        *reinterpret_cast<bf16x8*>(dbuf[bufi] + wbyte1) = pack8(xb0 - r1a, xb1 - r1b);
    };

    load_chunk(0);

    for (int t = 0; t < 16; ++t) {
        write_chunk(t & 1);
        __syncthreads();                       // writers done; prev readers of this buf past
        if (t < 15) load_chunk((t + 1) * 16);  // T14: issue next means loads early

        const char* buf = dbuf[t & 1];
        f32x4 acc[4];
        #pragma unroll
        for (int n = 0; n < 4; ++n) acc[n] = f32x4{0.f, 0.f, 0.f, 0.f};

        #pragma unroll
        for (int ks = 0; ks < 8; ++ks) {
            // B-frag: diff[class = lrow][e = 32ks + 8g ..)
            bf16x8 bfr = *reinterpret_cast<const bf16x8*>(
                buf + ((4 * ks + g) * 16 + (lrow ^ (g << 1))) * 16);
            #pragma unroll
            for (int n = 0; n < 4; ++n)
                acc[n] = __builtin_amdgcn_mfma_f32_16x16x32_bf16(greg[n][ks], bfr, acc[n], 0, 0, 0);
        }

        // epilogue: lane owns class c = 16t + lrow; sums T[d,c]*diff[c,d] over its 16 d's
        float p = 0.f;
        #pragma unroll
        for (int n = 0; n < 4; ++n) {
            const int d  = wn * 64 + n * 16 + g * 4;     // 4 consecutive d
            const int se = d >> 3;
            const int byte = (se * 16 + (lrow ^ ((se & 3) << 1))) * 16 + (d & 7) * 2;
            u32x2 dv = *reinterpret_cast<const u32x2*>(buf + byte);
            const float f0 = __uint_as_float(dv[0] << 16);
            const float f1 = __uint_as_float(dv[0] & 0xffff0000u);
            const float f2 = __uint_as_float(dv[1] << 16);
            const float f3 = __uint_as_float(dv[1] & 0xffff0000u);
            p += acc[n][0] * f0 + acc[n][1] * f1 + acc[n][2] * f2 + acc[n][3] * f3;
        }
        p += __shfl_xor(p, 16);
        p += __shfl_xor(p, 32);
        if (lane < 16) atomicAdd(&maha[t * 16 + lrow], p);
    }

    __syncthreads();
    const int c = cbase + tid;
    if (c < 1000) out[(size_t)b * 1000 + c] = maha[tid];   // raw maha; bias in k_soft
}

// per-batch log-softmax, in place on out (each element read+written by its own thread)
__global__ __launch_bounds__(256)
void k_soft(const float* __restrict__ bias, float* __restrict__ out)
{
    __shared__ float red[4];
    const int b = blockIdx.x, tid = threadIdx.x;
    const int lane = tid & 63, w = tid >> 6;
    float s[4];
    float mx = -3.4e38f;
    #pragma unroll
    for (int i = 0; i < 4; ++i) {
        const int c = tid + i * 256;
        if (c < 1000) {
            float v = -0.5f * out[(size_t)b * 1000 + c] + bias[c];
            s[i] = v; mx = fmaxf(mx, v);
        } else s[i] = -3.4e38f;
    }
    #pragma unroll
    for (int m = 1; m < 64; m <<= 1) mx = fmaxf(mx, __shfl_xor(mx, m));
    if (lane == 0) red[w] = mx;
    __syncthreads();
    const float bm = fmaxf(fmaxf(red[0], red[1]), fmaxf(red[2], red[3]));
    __syncthreads();
    float se = 0.f;
    #pragma unroll
    for (int i = 0; i < 4; ++i) {
        const int c = tid + i * 256;
        if (c < 1000) se += expf(s[i] - bm);
    }
    #pragma unroll
    for (int m = 1; m < 64; m <<= 1) se += __shfl_xor(se, m);
    if (lane == 0) red[w] = se;
    __syncthreads();
    const float lse = bm + logf(red[0] + red[1] + red[2] + red[3]);
    #pragma unroll
    for (int i = 0; i < 4; ++i) {
        const int c = tid + i * 256;
        if (c < 1000) out[(size_t)b * 1000 + c] = s[i] - lse;
    }
}

extern "C" void kernel_launch(void* const* d_in, const int* in_sizes, int n_in,
                              void* d_out, int out_size, void* d_ws, size_t ws_size,
                              hipStream_t stream)
{
    const float* x     = (const float*)d_in[0];
    const float* G     = (const float*)d_in[1];
    const float* lp    = (const float*)d_in[2];
    const float* means = (const float*)d_in[3];
    const float* clv   = (const float*)d_in[4];
    float* out  = (float*)d_out;
    float* bias = (float*)d_ws;   // 1000 f32

    k_prep<<<250, 256, 0, stream>>>(clv, lp, bias);
    k_main<<<1024, 256, 0, stream>>>(x, G, means, out);
    k_soft<<<256, 256, 0, stream>>>(bias, out);
}

// Round 11
// 165.417 us; speedup vs baseline: 1.1407x; 1.1045x over previous
//
#include <hip/hip_runtime.h>

#define LOG2PI 1.83787706640934548356f
#define NCONV 8192

typedef __attribute__((ext_vector_type(4))) float f32x4;
typedef __attribute__((ext_vector_type(8))) short bf16x8;
typedef __attribute__((ext_vector_type(2))) unsigned int u32x2;

__device__ __forceinline__ unsigned short f2bf(float f) {
    union { float f; unsigned u; } v; v.f = f;
    unsigned r = v.u + 0x7fffu + ((v.u >> 16) & 1u);   // RNE
    return (unsigned short)(r >> 16);
}
__device__ __forceinline__ bf16x8 pack8(f32x4 a, f32x4 b) {
    bf16x8 h;
    h[0]=(short)f2bf(a[0]); h[1]=(short)f2bf(a[1]); h[2]=(short)f2bf(a[2]); h[3]=(short)f2bf(a[3]);
    h[4]=(short)f2bf(b[0]); h[5]=(short)f2bf(b[1]); h[6]=(short)f2bf(b[2]); h[7]=(short)f2bf(b[3]);
    return h;
}

__device__ __forceinline__ void prep_body(const float* __restrict__ clv,
                                          const float* __restrict__ lp,
                                          float* __restrict__ bias, int cblk)
{
    const int w = threadIdx.x >> 6, lane = threadIdx.x & 63;
    const int c = cblk * 4 + w;
    if (c >= 1000) return;
    f32x4 v = *reinterpret_cast<const f32x4*>(clv + c * 256 + lane * 4);
    float s = v[0] + v[1] + v[2] + v[3];
    #pragma unroll
    for (int m = 1; m < 64; m <<= 1) s += __shfl_xor(s, m);
    if (lane == 0) bias[c] = lp[c] - 0.5f * (s + 256.0f * LOG2PI);
}

// Streaming G fp32 -> bf16 (row-major, same flat order) + k_prep folded in as tail blocks.
__global__ __launch_bounds__(256)
void k_convprep(const float* __restrict__ G, unsigned short* __restrict__ Gt,
                const float* __restrict__ clv, const float* __restrict__ lp,
                float* __restrict__ bias)
{
    const int bid = blockIdx.x;
    if (bid < NCONV) {
        const size_t i = ((size_t)bid * 256 + threadIdx.x) * 8;
        f32x4 a = *reinterpret_cast<const f32x4*>(G + i);
        f32x4 b = *reinterpret_cast<const f32x4*>(G + i + 4);
        *reinterpret_cast<bf16x8*>(Gt + i) = pack8(a, b);
    } else {
        prep_body(clv, lp, bias, bid - NCONV);
    }
}

__global__ __launch_bounds__(256)
void k_prep(const float* __restrict__ clv, const float* __restrict__ lp,
            float* __restrict__ bias)
{
    prep_body(clv, lp, bias, blockIdx.x);
}

// grid = 1024: b = bid&255, cg = bid>>8  => all 4 cg-blocks of batch b land on XCD b%8
// (cg0/cg1 co-resident share one L2 fetch of G_b; cg2/3 hit L3). Block = 256 thr = 4 waves.
// Wave wn owns d in [64wn, 64wn+64): greg[4][8] = 128 VGPR (full K in regs); BF16G path
// loads greg as 32 independent 16B loads (no pack, no serialization).
// LDS: double-buffered 16-class diff chunk, [slice s 0..31][row r 0..15][16B] with
// r ^= (s&3)<<1 swizzle (0 bank conflicts, verified r8) + maha[256].
// MFMA swapped (A=G, B=diff): lane owns ONE class -> epilogue = 4x ds_read_b64 +
// in-lane fma + 2 shfl + 1 LDS atomic. Class-split => maha flushed straight to out.
template <bool BF16G>
__global__ __launch_bounds__(256, 2)
void k_main(const float* __restrict__ x, const void* __restrict__ Gsrc,
            const float* __restrict__ means, float* __restrict__ out)
{
    __shared__ char dbuf[2][8192];
    __shared__ float maha[256];

    const int b     = blockIdx.x & 255;
    const int cg    = blockIdx.x >> 8;
    const int cbase = cg * 256;
    const int tid   = threadIdx.x;
    const int lane  = tid & 63;
    const int wn    = tid >> 6;          // wave = d-group
    const int lrow  = lane & 15;
    const int g     = lane >> 4;

    const float* xb = x + b * 256;

    maha[tid] = 0.f;

    // ---- G -> register A-fragments: greg[n][ks], lane holds
    //      G[d = 64wn + 16n + lrow][e = 32ks + 8g .. +8)
    bf16x8 greg[4][8];
    if constexpr (BF16G) {
        const unsigned short* Gb = (const unsigned short*)Gsrc + (size_t)b * 65536;
        #pragma unroll
        for (int n = 0; n < 4; ++n) {
            const unsigned short* rowp = Gb + (size_t)(wn * 64 + n * 16 + lrow) * 256 + g * 8;
            #pragma unroll
            for (int ks = 0; ks < 8; ++ks)
                greg[n][ks] = *reinterpret_cast<const bf16x8*>(rowp + ks * 32);
        }
    } else {
        const float* Gb = (const float*)Gsrc + (size_t)b * 65536;
        #pragma unroll
        for (int n = 0; n < 4; ++n) {
            const float* rowp = Gb + (size_t)(wn * 64 + n * 16 + lrow) * 256 + g * 8;
            #pragma unroll
            for (int ks = 0; ks < 8; ++ks) {
                f32x4 v0 = *reinterpret_cast<const f32x4*>(rowp + ks * 32);
                f32x4 v1 = *reinterpret_cast<const f32x4*>(rowp + ks * 32 + 4);
                greg[n][ks] = pack8(v0, v1);
            }
        }
    }

    // staging map: thread owns cells (s0, sr) and (s0+16, sr); cell = 8 e-values of one class
    const int sr = tid & 15;             // class row within 16-class chunk
    const int s0 = tid >> 4;             // slice 0..15
    const int e0 = s0 * 8, e1 = e0 + 128;
    const f32x4 xa0 = *reinterpret_cast<const f32x4*>(xb + e0);
    const f32x4 xa1 = *reinterpret_cast<const f32x4*>(xb + e0 + 4);
    const f32x4 xb0 = *reinterpret_cast<const f32x4*>(xb + e1);
    const f32x4 xb1 = *reinterpret_cast<const f32x4*>(xb + e1 + 4);
    const int wbyte0 = (s0 * 16 + (sr ^ ((s0 & 3) << 1))) * 16;   // (s0+16)&3 == s0&3
    const int wbyte1 = wbyte0 + 4096;

    f32x4 r0a, r0b, r1a, r1b;
    auto load_chunk = [&](int c0) {
        int cc = cbase + c0 + sr; if (cc > 999) cc = 999;
        const float* mp = means + (size_t)cc * 256;
        r0a = *reinterpret_cast<const f32x4*>(mp + e0);
        r0b = *reinterpret_cast<const f32x4*>(mp + e0 + 4);
        r1a = *reinterpret_cast<const f32x4*>(mp + e1);
        r1b = *reinterpret_cast<const f32x4*>(mp + e1 + 4);
    };
    auto write_chunk = [&](int bufi) {
        *reinterpret_cast<bf16x8*>(dbuf[bufi] + wbyte0) = pack8(xa0 - r0a, xa1 - r0b);
        *reinterpret_cast<bf16x8*>(dbuf[bufi] + wbyte1) = pack8(xb0 - r1a, xb1 - r1b);
    };

    load_chunk(0);

    for (int t = 0; t < 16; ++t) {
        write_chunk(t & 1);
        __syncthreads();                       // writers done; prev readers of this buf past
        if (t < 15) load_chunk((t + 1) * 16);  // T14: issue next means loads early

        const char* buf = dbuf[t & 1];
        f32x4 acc[4];
        #pragma unroll
        for (int n = 0; n < 4; ++n) acc[n] = f32x4{0.f, 0.f, 0.f, 0.f};

        #pragma unroll
        for (int ks = 0; ks < 8; ++ks) {
            // B-frag: diff[class = lrow][e = 32ks + 8g ..)
            bf16x8 bfr = *reinterpret_cast<const bf16x8*>(
                buf + ((4 * ks + g) * 16 + (lrow ^ (g << 1))) * 16);
            #pragma unroll
            for (int n = 0; n < 4; ++n)
                acc[n] = __builtin_amdgcn_mfma_f32_16x16x32_bf16(greg[n][ks], bfr, acc[n], 0, 0, 0);
        }

        // epilogue: lane owns class c = 16t + lrow; sums T[d,c]*diff[c,d] over its 16 d's
        float p = 0.f;
        #pragma unroll
        for (int n = 0; n < 4; ++n) {
            const int d  = wn * 64 + n * 16 + g * 4;     // 4 consecutive d
            const int se = d >> 3;
            const int byte = (se * 16 + (lrow ^ ((se & 3) << 1))) * 16 + (d & 7) * 2;
            u32x2 dv = *reinterpret_cast<const u32x2*>(buf + byte);
            const float f0 = __uint_as_float(dv[0] << 16);
            const float f1 = __uint_as_float(dv[0] & 0xffff0000u);
            const float f2 = __uint_as_float(dv[1] << 16);
            const float f3 = __uint_as_float(dv[1] & 0xffff0000u);
            p += acc[n][0] * f0 + acc[n][1] * f1 + acc[n][2] * f2 + acc[n][3] * f3;
        }
        p += __shfl_xor(p, 16);
        p += __shfl_xor(p, 32);
        if (lane < 16) atomicAdd(&maha[t * 16 + lrow], p);
    }

    __syncthreads();
    const int c = cbase + tid;
    if (c < 1000) out[(size_t)b * 1000 + c] = maha[tid];   // raw maha; bias in k_soft
}

// per-batch log-softmax, in place on out (each element read+written by its own thread)
__global__ __launch_bounds__(256)
void k_soft(const float* __restrict__ bias, float* __restrict__ out)
{
    __shared__ float red[4];
    const int b = blockIdx.x, tid = threadIdx.x;
    const int lane = tid & 63, w = tid >> 6;
    float s[4];
    float mx = -3.4e38f;
    #pragma unroll
    for (int i = 0; i < 4; ++i) {
        const int c = tid + i * 256;
        if (c < 1000) {
            float v = -0.5f * out[(size_t)b * 1000 + c] + bias[c];
            s[i] = v; mx = fmaxf(mx, v);
        } else s[i] = -3.4e38f;
    }
    #pragma unroll
    for (int m = 1; m < 64; m <<= 1) mx = fmaxf(mx, __shfl_xor(mx, m));
    if (lane == 0) red[w] = mx;
    __syncthreads();
    const float bm = fmaxf(fmaxf(red[0], red[1]), fmaxf(red[2], red[3]));
    __syncthreads();
    float se = 0.f;
    #pragma unroll
    for (int i = 0; i < 4; ++i) {
        const int c = tid + i * 256;
        if (c < 1000) se += expf(s[i] - bm);
    }
    #pragma unroll
    for (int m = 1; m < 64; m <<= 1) se += __shfl_xor(se, m);
    if (lane == 0) red[w] = se;
    __syncthreads();
    const float lse = bm + logf(red[0] + red[1] + red[2] + red[3]);
    #pragma unroll
    for (int i = 0; i < 4; ++i) {
        const int c = tid + i * 256;
        if (c < 1000) out[(size_t)b * 1000 + c] = s[i] - lse;
    }
}

extern "C" void kernel_launch(void* const* d_in, const int* in_sizes, int n_in,
                              void* d_out, int out_size, void* d_ws, size_t ws_size,
                              hipStream_t stream)
{
    const float* x     = (const float*)d_in[0];
    const float* G     = (const float*)d_in[1];
    const float* lp    = (const float*)d_in[2];
    const float* means = (const float*)d_in[3];
    const float* clv   = (const float*)d_in[4];
    float* out = (float*)d_out;

    const size_t need = (size_t)16777216 * 2 + 4096;   // Gt bf16 + bias
    if (ws_size >= need) {
        unsigned short* Gt = (unsigned short*)d_ws;
        float* bias = (float*)((char*)d_ws + (size_t)16777216 * 2);
        k_convprep<<<NCONV + 250, 256, 0, stream>>>(G, Gt, clv, lp, bias);
        k_main<true><<<1024, 256, 0, stream>>>(x, (const void*)Gt, means, out);
        k_soft<<<256, 256, 0, stream>>>(bias, out);
    } else {
        float* bias = (float*)d_ws;   // 1000 f32
        k_prep<<<250, 256, 0, stream>>>(clv, lp, bias);
        k_main<false><<<1024, 256, 0, stream>>>(x, (const void*)G, means, out);
        k_soft<<<256, 256, 0, stream>>>(bias, out);
    }
}

// Round 12
// 160.880 us; speedup vs baseline: 1.1729x; 1.0282x over previous
//
#include <hip/hip_runtime.h>

#define LOG2PI 1.83787706640934548356f
#define NCONV 8192

typedef __attribute__((ext_vector_type(4))) float f32x4;
typedef __attribute__((ext_vector_type(8))) short bf16x8;
typedef __attribute__((ext_vector_type(2))) unsigned int u32x2;

__device__ __forceinline__ unsigned short f2bf(float f) {
    union { float f; unsigned u; } v; v.f = f;
    unsigned r = v.u + 0x7fffu + ((v.u >> 16) & 1u);   // RNE
    return (unsigned short)(r >> 16);
}
__device__ __forceinline__ bf16x8 pack8(f32x4 a, f32x4 b) {
    bf16x8 h;
    h[0]=(short)f2bf(a[0]); h[1]=(short)f2bf(a[1]); h[2]=(short)f2bf(a[2]); h[3]=(short)f2bf(a[3]);
    h[4]=(short)f2bf(b[0]); h[5]=(short)f2bf(b[1]); h[6]=(short)f2bf(b[2]); h[7]=(short)f2bf(b[3]);
    return h;
}

__device__ __forceinline__ void prep_body(const float* __restrict__ clv,
                                          const float* __restrict__ lp,
                                          float* __restrict__ bias, int cblk)
{
    const int w = threadIdx.x >> 6, lane = threadIdx.x & 63;
    const int c = cblk * 4 + w;
    if (c >= 1000) return;
    f32x4 v = *reinterpret_cast<const f32x4*>(clv + c * 256 + lane * 4);
    float s = v[0] + v[1] + v[2] + v[3];
    #pragma unroll
    for (int m = 1; m < 64; m <<= 1) s += __shfl_xor(s, m);
    if (lane == 0) bias[c] = lp[c] - 0.5f * (s + 256.0f * LOG2PI);
}

// Streaming G fp32 -> bf16 (row-major, same flat order) + k_prep folded in as tail blocks.
__global__ __launch_bounds__(256)
void k_convprep(const float* __restrict__ G, unsigned short* __restrict__ Gt,
                const float* __restrict__ clv, const float* __restrict__ lp,
                float* __restrict__ bias)
{
    const int bid = blockIdx.x;
    if (bid < NCONV) {
        const size_t i = ((size_t)bid * 256 + threadIdx.x) * 8;
        f32x4 a = *reinterpret_cast<const f32x4*>(G + i);
        f32x4 b = *reinterpret_cast<const f32x4*>(G + i + 4);
        *reinterpret_cast<bf16x8*>(Gt + i) = pack8(a, b);
    } else {
        prep_body(clv, lp, bias, bid - NCONV);
    }
}

__global__ __launch_bounds__(256)
void k_prep(const float* __restrict__ clv, const float* __restrict__ lp,
            float* __restrict__ bias)
{
    prep_body(clv, lp, bias, blockIdx.x);
}

// grid = 1024: b = bid&255, cg = bid>>8 (XCD affinity: batch's 4 cg-blocks share G_b in L2/L3).
// Block = 256 thr = 4 waves; wave wn owns d in [64wn, 64wn+64); greg[4][8] in AGPRs.
// r12 change: 32-class chunks, 8 barrier iterations (was 16x16) — 64 MFMA/wave/barrier,
// two 16-class halves reuse the same acc regs. LDS: dbuf 2x16KB, layout
// [slice 0..31][row 0..31][16B], row XOR (slice&3)<<1 (conflict-free, scaled from r8) + maha.
// Epilogue per half: lane owns one class -> 4x ds_read_b64 + fma + 2 shfl + LDS atomic.
template <bool BF16G>
__global__ __launch_bounds__(256, 2)
void k_main(const float* __restrict__ x, const void* __restrict__ Gsrc,
            const float* __restrict__ means, float* __restrict__ out)
{
    __shared__ char dbuf[2][16384];
    __shared__ float maha[256];

    const int b     = blockIdx.x & 255;
    const int cg    = blockIdx.x >> 8;
    const int cbase = cg * 256;
    const int tid   = threadIdx.x;
    const int lane  = tid & 63;
    const int wn    = tid >> 6;          // wave = d-group
    const int lrow  = lane & 15;
    const int g     = lane >> 4;

    const float* xb = x + b * 256;

    maha[tid] = 0.f;

    // ---- G -> register A-fragments: greg[n][ks], lane holds
    //      G[d = 64wn + 16n + lrow][e = 32ks + 8g .. +8)
    bf16x8 greg[4][8];
    if constexpr (BF16G) {
        const unsigned short* Gb = (const unsigned short*)Gsrc + (size_t)b * 65536;
        #pragma unroll
        for (int n = 0; n < 4; ++n) {
            const unsigned short* rowp = Gb + (size_t)(wn * 64 + n * 16 + lrow) * 256 + g * 8;
            #pragma unroll
            for (int ks = 0; ks < 8; ++ks)
                greg[n][ks] = *reinterpret_cast<const bf16x8*>(rowp + ks * 32);
        }
    } else {
        const float* Gb = (const float*)Gsrc + (size_t)b * 65536;
        #pragma unroll
        for (int n = 0; n < 4; ++n) {
            const float* rowp = Gb + (size_t)(wn * 64 + n * 16 + lrow) * 256 + g * 8;
            #pragma unroll
            for (int ks = 0; ks < 8; ++ks) {
                f32x4 v0 = *reinterpret_cast<const f32x4*>(rowp + ks * 32);
                f32x4 v1 = *reinterpret_cast<const f32x4*>(rowp + ks * 32 + 4);
                greg[n][ks] = pack8(v0, v1);
            }
        }
    }

    // staging map: thread owns 4 cells: (s0, sr), (s0, sr+16), (s0+16, sr), (s0+16, sr+16)
    // cell (s,r) = 8 e-values (e = 8s..) of class (c0 + r); 32-class chunk = 16 KB
    const int sr = tid & 15;
    const int s0 = tid >> 4;             // slice 0..15 (thread also covers s0+16)
    const int e0 = s0 * 8, e1 = e0 + 128;
    const f32x4 xa0 = *reinterpret_cast<const f32x4*>(xb + e0);
    const f32x4 xa1 = *reinterpret_cast<const f32x4*>(xb + e0 + 4);
    const f32x4 xb0 = *reinterpret_cast<const f32x4*>(xb + e1);
    const f32x4 xb1 = *reinterpret_cast<const f32x4*>(xb + e1 + 4);
    const int wb00 = (s0 * 32 + (sr ^ ((s0 & 3) << 1))) * 16;   // (s0, sr)
    // (s0, sr+16) = wb00+256 ; (s0+16, sr) = wb00+8192 ; (s0+16, sr+16) = wb00+8448

    f32x4 r0a, r0b, r1a, r1b, r2a, r2b, r3a, r3b;
    auto load_chunk = [&](int c0) {
        int cc0 = cbase + c0 + sr;      if (cc0 > 999) cc0 = 999;
        int cc1 = cbase + c0 + sr + 16; if (cc1 > 999) cc1 = 999;
        const float* mp0 = means + (size_t)cc0 * 256;
        const float* mp1 = means + (size_t)cc1 * 256;
        r0a = *reinterpret_cast<const f32x4*>(mp0 + e0);
        r0b = *reinterpret_cast<const f32x4*>(mp0 + e0 + 4);
        r1a = *reinterpret_cast<const f32x4*>(mp0 + e1);
        r1b = *reinterpret_cast<const f32x4*>(mp0 + e1 + 4);
        r2a = *reinterpret_cast<const f32x4*>(mp1 + e0);
        r2b = *reinterpret_cast<const f32x4*>(mp1 + e0 + 4);
        r3a = *reinterpret_cast<const f32x4*>(mp1 + e1);
        r3b = *reinterpret_cast<const f32x4*>(mp1 + e1 + 4);
    };
    auto write_chunk = [&](int bufi) {
        char* base = dbuf[bufi];
        *reinterpret_cast<bf16x8*>(base + wb00)        = pack8(xa0 - r0a, xa1 - r0b);
        *reinterpret_cast<bf16x8*>(base + wb00 + 256)  = pack8(xa0 - r2a, xa1 - r2b);
        *reinterpret_cast<bf16x8*>(base + wb00 + 8192) = pack8(xb0 - r1a, xb1 - r1b);
        *reinterpret_cast<bf16x8*>(base + wb00 + 8448) = pack8(xb0 - r3a, xb1 - r3b);
    };

    load_chunk(0);

    for (int t = 0; t < 8; ++t) {
        write_chunk(t & 1);
        __syncthreads();                       // single barrier per 32-class chunk
        if (t < 7) load_chunk((t + 1) * 32);   // T14: issue next means loads early

        const char* buf = dbuf[t & 1];

        #pragma unroll
        for (int h = 0; h < 2; ++h) {          // two 16-class halves, acc regs reused
            f32x4 acc[4];
            #pragma unroll
            for (int n = 0; n < 4; ++n) acc[n] = f32x4{0.f, 0.f, 0.f, 0.f};

            #pragma unroll
            for (int ks = 0; ks < 8; ++ks) {
                // B-frag: diff[class = 16h + lrow][e = 32ks + 8g ..)
                bf16x8 bfr = *reinterpret_cast<const bf16x8*>(
                    buf + (((4 * ks + g) * 32) + h * 16 + (lrow ^ (g << 1))) * 16);
                #pragma unroll
                for (int n = 0; n < 4; ++n)
                    acc[n] = __builtin_amdgcn_mfma_f32_16x16x32_bf16(greg[n][ks], bfr, acc[n], 0, 0, 0);
            }

            // epilogue: lane owns class c = 32t + 16h + lrow
            float p = 0.f;
            #pragma unroll
            for (int n = 0; n < 4; ++n) {
                const int d  = wn * 64 + n * 16 + g * 4;     // 4 consecutive d
                const int se = d >> 3;                       // slice 0..31
                const int byte = (se * 32 + h * 16 + (lrow ^ ((se & 3) << 1))) * 16 + (d & 7) * 2;
                u32x2 dv = *reinterpret_cast<const u32x2*>(buf + byte);
                const float f0 = __uint_as_float(dv[0] << 16);
                const float f1 = __uint_as_float(dv[0] & 0xffff0000u);
                const float f2 = __uint_as_float(dv[1] << 16);
                const float f3 = __uint_as_float(dv[1] & 0xffff0000u);
                p += acc[n][0] * f0 + acc[n][1] * f1 + acc[n][2] * f2 + acc[n][3] * f3;
            }
            p += __shfl_xor(p, 16);
            p += __shfl_xor(p, 32);
            if (lane < 16) atomicAdd(&maha[t * 32 + h * 16 + lrow], p);
        }
    }

    __syncthreads();
    const int c = cbase + tid;
    if (c < 1000) out[(size_t)b * 1000 + c] = maha[tid];   // raw maha; bias in k_soft
}

// per-batch log-softmax, in place on out (each element read+written by its own thread)
__global__ __launch_bounds__(256)
void k_soft(const float* __restrict__ bias, float* __restrict__ out)
{
    __shared__ float red[4];
    const int b = blockIdx.x, tid = threadIdx.x;
    const int lane = tid & 63, w = tid >> 6;
    float s[4];
    float mx = -3.4e38f;
    #pragma unroll
    for (int i = 0; i < 4; ++i) {
        const int c = tid + i * 256;
        if (c < 1000) {
            float v = -0.5f * out[(size_t)b * 1000 + c] + bias[c];
            s[i] = v; mx = fmaxf(mx, v);
        } else s[i] = -3.4e38f;
    }
    #pragma unroll
    for (int m = 1; m < 64; m <<= 1) mx = fmaxf(mx, __shfl_xor(mx, m));
    if (lane == 0) red[w] = mx;
    __syncthreads();
    const float bm = fmaxf(fmaxf(red[0], red[1]), fmaxf(red[2], red[3]));
    __syncthreads();
    float se = 0.f;
    #pragma unroll
    for (int i = 0; i < 4; ++i) {
        const int c = tid + i * 256;
        if (c < 1000) se += expf(s[i] - bm);
    }
    #pragma unroll
    for (int m = 1; m < 64; m <<= 1) se += __shfl_xor(se, m);
    if (lane == 0) red[w] = se;
    __syncthreads();
    const float lse = bm + logf(red[0] + red[1] + red[2] + red[3]);
    #pragma unroll
    for (int i = 0; i < 4; ++i) {
        const int c = tid + i * 256;
        if (c < 1000) out[(size_t)b * 1000 + c] = s[i] - lse;
    }
}

extern "C" void kernel_launch(void* const* d_in, const int* in_sizes, int n_in,
                              void* d_out, int out_size, void* d_ws, size_t ws_size,
                              hipStream_t stream)
{
    const float* x     = (const float*)d_in[0];
    const float* G     = (const float*)d_in[1];
    const float* lp    = (const float*)d_in[2];
    const float* means = (const float*)d_in[3];
    const float* clv   = (const float*)d_in[4];
    float* out = (float*)d_out;

    const size_t need = (size_t)16777216 * 2 + 4096;   // Gt bf16 + bias
    if (ws_size >= need) {
        unsigned short* Gt = (unsigned short*)d_ws;
        float* bias = (float*)((char*)d_ws + (size_t)16777216 * 2);
        k_convprep<<<NCONV + 250, 256, 0, stream>>>(G, Gt, clv, lp, bias);
        k_main<true><<<1024, 256, 0, stream>>>(x, (const void*)Gt, means, out);
        k_soft<<<256, 256, 0, stream>>>(bias, out);
    } else {
        float* bias = (float*)d_ws;   // 1000 f32
        k_prep<<<250, 256, 0, stream>>>(clv, lp, bias);
        k_main<false><<<1024, 256, 0, stream>>>(x, (const void*)G, means, out);
        k_soft<<<256, 256, 0, stream>>>(bias, out);
    }
}